// Round 1
// baseline (14728.432 us; speedup 1.0000x reference)
//
#include <hip/hip_runtime.h>

// 3-layer LSTM, H=64, B=256, S=4096, DIN=1, + linear head to 1 output.
// One block per batch element (256 blocks, 1/CU). Block = 768 threads = 3
// groups of 256; group l owns layer l, pipelined with skew: at tick t,
// group l computes its layer's timestep (t - l). Weights in registers
// (thread = one gate row, fully unrolled). h vectors exchanged via LDS.

#define SQ 4096
#define HH 64
#define NB 256

__device__ __forceinline__ float sigm(float x) {
    return 1.0f / (1.0f + __expf(-x));
}
__device__ __forceinline__ float tanh_f(float x) {
    x = fminf(fmaxf(x, -30.0f), 30.0f);
    float e = __expf(2.0f * x);
    return (e - 1.0f) / (e + 1.0f);
}

__global__ __launch_bounds__(768, 3) void lstm3_fused(
    const float* __restrict__ x,
    const float* __restrict__ Wih0, const float* __restrict__ Whh0,
    const float* __restrict__ bih0, const float* __restrict__ bhh0,
    const float* __restrict__ Wih1, const float* __restrict__ Whh1,
    const float* __restrict__ bih1, const float* __restrict__ bhh1,
    const float* __restrict__ Wih2, const float* __restrict__ Whh2,
    const float* __restrict__ bih2, const float* __restrict__ bhh2,
    const float* __restrict__ Wlin, const float* __restrict__ blin,
    float* __restrict__ out)
{
    const int b   = blockIdx.x;
    const int tid = threadIdx.x;
    const int gid = tid >> 8;    // layer group 0,1,2
    const int row = tid & 255;   // gate row within layer

    __shared__ __align__(16) float xrow[SQ];
    __shared__ __align__(16) float h0buf[HH];
    __shared__ __align__(16) float h1buf[HH];
    __shared__ __align__(16) float h2buf[HH];
    __shared__ __align__(16) float g0buf[256];
    __shared__ __align__(16) float g1buf[256];
    __shared__ __align__(16) float g2buf[256];

    // Stage this batch element's entire input row into LDS (DIN==1).
    for (int i = tid; i < SQ; i += 768) xrow[i] = x[b * SQ + i];
    if (tid < HH) { h0buf[tid] = 0.0f; h1buf[tid] = 0.0f; h2buf[tid] = 0.0f; }

    // Per-thread weight rows in registers.
    float wa[64];   // gid0: Whh0 row | gid1: Wih1 row | gid2: Wih2 row
    float wb[64];   // gid1: Whh1 row | gid2: Whh2 row   (unused by gid0)
    float bias = 0.0f, wih0 = 0.0f;

    if (gid == 0) {
        bias = bih0[row] + bhh0[row];
        wih0 = Wih0[row];                       // [256,1]
        const float4* W = (const float4*)(Whh0 + row * 64);
#pragma unroll
        for (int j = 0; j < 16; ++j) {
            float4 v = W[j];
            wa[4*j] = v.x; wa[4*j+1] = v.y; wa[4*j+2] = v.z; wa[4*j+3] = v.w;
        }
    } else if (gid == 1) {
        bias = bih1[row] + bhh1[row];
        const float4* Wi = (const float4*)(Wih1 + row * 64);
        const float4* Wh = (const float4*)(Whh1 + row * 64);
#pragma unroll
        for (int j = 0; j < 16; ++j) {
            float4 v = Wi[j];
            wa[4*j] = v.x; wa[4*j+1] = v.y; wa[4*j+2] = v.z; wa[4*j+3] = v.w;
        }
#pragma unroll
        for (int j = 0; j < 16; ++j) {
            float4 v = Wh[j];
            wb[4*j] = v.x; wb[4*j+1] = v.y; wb[4*j+2] = v.z; wb[4*j+3] = v.w;
        }
    } else {
        bias = bih2[row] + bhh2[row];
        const float4* Wi = (const float4*)(Wih2 + row * 64);
        const float4* Wh = (const float4*)(Whh2 + row * 64);
#pragma unroll
        for (int j = 0; j < 16; ++j) {
            float4 v = Wi[j];
            wa[4*j] = v.x; wa[4*j+1] = v.y; wa[4*j+2] = v.z; wa[4*j+3] = v.w;
        }
#pragma unroll
        for (int j = 0; j < 16; ++j) {
            float4 v = Wh[j];
            wb[4*j] = v.x; wb[4*j+1] = v.y; wb[4*j+2] = v.z; wb[4*j+3] = v.w;
        }
    }

    float c_reg = 0.0f;              // cell state, held by combine threads (row<64)
    float wlin_k = 0.0f, blin_v = 0.0f;
    if (gid == 2 && row < HH) { wlin_k = Wlin[row]; blin_v = blin[0]; }

    __syncthreads();

    for (int t = 0; t < SQ + 2; ++t) {
        // ---------------- Phase A: gate matvec ----------------
        if (gid == 0) {
            if (t < SQ) {
                float a0 = bias + wih0 * xrow[t], a1 = 0.f, a2 = 0.f, a3 = 0.f;
                const float4* hp = (const float4*)h0buf;
#pragma unroll
                for (int j = 0; j < 16; ++j) {
                    float4 v = hp[j];
                    a0 += wa[4*j+0] * v.x; a1 += wa[4*j+1] * v.y;
                    a2 += wa[4*j+2] * v.z; a3 += wa[4*j+3] * v.w;
                }
                g0buf[row] = (a0 + a1) + (a2 + a3);
            }
        } else if (gid == 1) {
            if (t >= 1 && t <= SQ) {
                float a0 = bias, a1 = 0.f, a2 = 0.f, a3 = 0.f;
                const float4* hp = (const float4*)h0buf;   // layer-0 output, step t-1
                const float4* hq = (const float4*)h1buf;   // own state, step t-2
#pragma unroll
                for (int j = 0; j < 16; ++j) {
                    float4 v = hp[j];
                    a0 += wa[4*j+0] * v.x; a1 += wa[4*j+1] * v.y;
                    a2 += wa[4*j+2] * v.z; a3 += wa[4*j+3] * v.w;
                }
#pragma unroll
                for (int j = 0; j < 16; ++j) {
                    float4 v = hq[j];
                    a0 += wb[4*j+0] * v.x; a1 += wb[4*j+1] * v.y;
                    a2 += wb[4*j+2] * v.z; a3 += wb[4*j+3] * v.w;
                }
                g1buf[row] = (a0 + a1) + (a2 + a3);
            }
        } else {
            if (t >= 2) {
                float a0 = bias, a1 = 0.f, a2 = 0.f, a3 = 0.f;
                const float4* hp = (const float4*)h1buf;   // layer-1 output, step t-2
                const float4* hq = (const float4*)h2buf;   // own state, step t-3
#pragma unroll
                for (int j = 0; j < 16; ++j) {
                    float4 v = hp[j];
                    a0 += wa[4*j+0] * v.x; a1 += wa[4*j+1] * v.y;
                    a2 += wa[4*j+2] * v.z; a3 += wa[4*j+3] * v.w;
                }
#pragma unroll
                for (int j = 0; j < 16; ++j) {
                    float4 v = hq[j];
                    a0 += wb[4*j+0] * v.x; a1 += wb[4*j+1] * v.y;
                    a2 += wb[4*j+2] * v.z; a3 += wb[4*j+3] * v.w;
                }
                g2buf[row] = (a0 + a1) + (a2 + a3);
            }
        }
        __syncthreads();

        // ---------------- Phase B: gate combine + state update ----------------
        if (row < HH) {
            const int step = t - gid;
            if (step >= 0 && step < SQ) {
                const float* gb = (gid == 0) ? g0buf : (gid == 1) ? g1buf : g2buf;
                float gi = gb[row], gf = gb[64 + row], gg = gb[128 + row], go = gb[192 + row];
                float c = sigm(gf) * c_reg + sigm(gi) * tanh_f(gg);
                float h = sigm(go) * tanh_f(c);
                c_reg = c;
                float* hb = (gid == 0) ? h0buf : (gid == 1) ? h1buf : h2buf;
                hb[row] = h;

                if (gid == 2) {
                    // y[b, step] = dot(Wlin, h2) + blin  (64-lane butterfly)
                    float v = wlin_k * h;
#pragma unroll
                    for (int m = 1; m < 64; m <<= 1) v += __shfl_xor(v, m, 64);
                    if (row == 0) out[b * SQ + step] = v + blin_v;
                }
                if (step == SQ - 1) {
                    // h_n / c_n: [3, B, H] each, after y ([B,S,1]).
                    out[NB * SQ + gid * NB * HH + b * HH + row] = h;
                    out[NB * SQ + 3 * NB * HH + gid * NB * HH + b * HH + row] = c;
                }
            }
        }
        __syncthreads();
    }
}

extern "C" void kernel_launch(void* const* d_in, const int* in_sizes, int n_in,
                              void* d_out, int out_size, void* d_ws, size_t ws_size,
                              hipStream_t stream) {
    const float* x    = (const float*)d_in[0];
    const float* Wih0 = (const float*)d_in[1];
    const float* Whh0 = (const float*)d_in[2];
    const float* bih0 = (const float*)d_in[3];
    const float* bhh0 = (const float*)d_in[4];
    const float* Wih1 = (const float*)d_in[5];
    const float* Whh1 = (const float*)d_in[6];
    const float* bih1 = (const float*)d_in[7];
    const float* bhh1 = (const float*)d_in[8];
    const float* Wih2 = (const float*)d_in[9];
    const float* Whh2 = (const float*)d_in[10];
    const float* bih2 = (const float*)d_in[11];
    const float* bhh2 = (const float*)d_in[12];
    const float* Wlin = (const float*)d_in[13];
    const float* blin = (const float*)d_in[14];
    float* out = (float*)d_out;

    lstm3_fused<<<NB, 768, 0, stream>>>(x, Wih0, Whh0, bih0, bhh0,
                                        Wih1, Whh1, bih1, bhh1,
                                        Wih2, Whh2, bih2, bhh2,
                                        Wlin, blin, out);
}